// Round 5
// baseline (237.961 us; speedup 1.0000x reference)
//
#include <hip/hip_runtime.h>
#include <math.h>

// x: (16, 512, 512, 8) float32 NHWC. float4 granule: ((n*512+h)*512+w)*2+c4.
//
// v5: FULL-ROW LINEAR STREAMING. R0-R4 evidence: four structures all at
// 80-87us, all pipes <40%, MLP proven ample (R0: 480KB/CU in flight) ->
// the memory system delivers only ~2.6TB/s for the 2KB-chunk/4KB-stride
// request pattern (vs 6.3TB/s linear copy, m13). This version makes every
// block's sweep fully linear: block = 1024 threads = one whole (w,c4) row
// (16KB contiguous per row load/store), marching down 16 h-rows. LDS =
// 4-row ring (64KB, 2 blocks/CU). w+-1 via LDS; h-rolling history in regs
// (v1's verified recurrence). Prefetch issued at iter top, ds_write at
// iter bottom (latency hides under compute; sibling block covers barrier).

constexpr int Hdim  = 512;
constexpr int Wdim  = 512;
constexpr int ROWF4 = Wdim * 2;      // 1024 f4 per h-row
constexpr int TH    = 16;            // output rows per block
constexpr int NSLOT = 4;             // LDS row ring

typedef float floatx4 __attribute__((ext_vector_type(4)));

__device__ __forceinline__ float4 f4max(float4 a, float4 b) {
    return make_float4(fmaxf(a.x,b.x), fmaxf(a.y,b.y), fmaxf(a.z,b.z), fmaxf(a.w,b.w));
}

__device__ __forceinline__ void nt_store_f4(float4* p, float4 v) {
    floatx4 nv; nv.x = v.x; nv.y = v.y; nv.z = v.z; nv.w = v.w;
    __builtin_nontemporal_store(nv, reinterpret_cast<floatx4*>(p));
}

__global__ __launch_bounds__(1024, 8) void nms_kernel(
    const float4* __restrict__ x,
    const unsigned char* __restrict__ mask_bytes,
    float4* __restrict__ out)
{
    __shared__ float4 L[NSLOT][ROWF4];   // 4*1024*16 = 65536 B

    // ---- Decode 3x3 boolean mask robustly (int32 vs 1-byte bool layout).
    const int* mi = (const int*)mask_bytes;
    bool intlay = true;
    #pragma unroll
    for (int i = 0; i < 9; ++i) { int v = mi[i]; intlay = intlay && (v == 0 || v == 1); }
    bool m[9];
    #pragma unroll
    for (int i = 0; i < 9; ++i) m[i] = intlay ? (mi[i] != 0) : (mask_bytes[i] != 0);

    const float4 NEG = make_float4(-INFINITY, -INFINITY, -INFINITY, -INFINITY);

    int b  = blockIdx.x;
    int hg = b & 31;             // 32 h-groups of 16
    int n  = b >> 5;
    int h0 = hg * TH;
    int t  = threadIdx.x;        // f4 column within row: c4 = t&1, w = t>>1
    bool topb = (hg == 0);
    bool botb = (hg == 31);

    bool aok = (t >= 2);                 // w > 0
    bool cok = (t <= ROWF4 - 3);         // w < 511
    int ia = aok ? t - 2 : t;            // clamped LDS col (value NEG-fixed)
    int ic = cok ? t + 2 : t;

    int xbase = n * Hdim * ROWF4;        // max ~8.4M, fits int

    // ---- Prologue: rows h0-1, h0, h0+1 -> slots 0,1,2 (loads burst first).
    {
        int r0 = topb ? 0 : h0 - 1;      // clamped; value killed by R0=NEG at r=0
        float4 v0 = x[xbase + r0 * ROWF4 + t];
        float4 v1 = x[xbase + h0 * ROWF4 + t];
        float4 v2 = x[xbase + (h0 + 1) * ROWF4 + t];
        L[0][t] = v0; L[1][t] = v1; L[2][t] = v2;
    }
    __syncthreads();

    // Rolling history (verified recurrence from v1):
    //   output s uses R0(row s-1) [two back], R1(row s) [one back],
    //   R2(row s+1) [current], center = b(row s) [one back].
    float4 R0a = NEG, R0b = NEG, R1b = NEG, CTb = NEG;

    #pragma unroll
    for (int r = 0; r < TH + 2; ++r) {
        // Issue next row's global load FIRST (latency hides under compute).
        float4 pf;
        const bool doPf = (r <= TH - 2);
        if (doPf) {
            int hp = h0 + 2 + r;                       // rows h0+2 .. h0+16
            if (hp > Hdim - 1) hp = Hdim - 1;          // botb only; value killed by R2=NEG
            pf = x[xbase + hp * ROWF4 + t];
        }

        // Current row hr = h0-1+r from ring slot r&3.
        const int s = r & 3;
        float4 a  = L[s][ia];
        float4 bb = L[s][t];
        float4 c  = L[s][ic];
        a.x = aok ? a.x : -INFINITY; a.y = aok ? a.y : -INFINITY;
        a.z = aok ? a.z : -INFINITY; a.w = aok ? a.w : -INFINITY;
        c.x = cok ? c.x : -INFINITY; c.y = cok ? c.y : -INFINITY;
        c.z = cok ? c.z : -INFINITY; c.w = cok ? c.w : -INFINITY;

        float4 R0 = NEG, R1 = NEG, R2 = NEG;
        if (m[0]) R0 = f4max(R0, a);
        if (m[1]) R0 = f4max(R0, bb);
        if (m[2]) R0 = f4max(R0, c);
        if (m[3]) R1 = f4max(R1, a);
        if (m[4]) R1 = f4max(R1, bb);
        if (m[5]) R1 = f4max(R1, c);
        if (m[6]) R2 = f4max(R2, a);
        if (m[7]) R2 = f4max(R2, bb);
        if (m[8]) R2 = f4max(R2, c);
        if (r == 0 && topb)      R0 = NEG;   // row h0-1 doesn't exist
        if (r == TH + 1 && botb) R2 = NEG;   // row h0+16 doesn't exist

        if (r >= 2) {
            float4 mm  = f4max(f4max(R0a, R1b), R2);
            float4 ctr = CTb;
            float4 o;
            o.x = (ctr.x > mm.x) ? ctr.x : 0.0f;
            o.y = (ctr.y > mm.y) ? ctr.y : 0.0f;
            o.z = (ctr.z > mm.z) ? ctr.z : 0.0f;
            o.w = (ctr.w > mm.w) ? ctr.w : 0.0f;
            nt_store_f4(&out[xbase + (h0 + r - 2) * ROWF4 + t], o);
        }

        R0a = R0b; R0b = R0; R1b = R1; CTb = bb;

        // Land the prefetched row into the ring (vmcnt wait happens here),
        // then barrier. Slot (r+3)&3 was last read at iter r-1 (1 barrier ago).
        if (doPf) L[(r + 3) & 3][t] = pf;
        __syncthreads();
    }
}

extern "C" void kernel_launch(void* const* d_in, const int* in_sizes, int n_in,
                              void* d_out, int out_size, void* d_ws, size_t ws_size,
                              hipStream_t stream) {
    const float4* x = (const float4*)d_in[0];
    const unsigned char* mask = (const unsigned char*)d_in[1];
    float4* out = (float4*)d_out;

    // 16 n x 32 hg = 512 blocks of 1024 threads (2 blocks/CU, zero tail).
    int grid = 16 * (Hdim / TH);
    int block = 1024;
    nms_kernel<<<grid, block, 0, stream>>>(x, mask, out);
}